// Round 1
// baseline (145.545 us; speedup 1.0000x reference)
//
#include <hip/hip_runtime.h>
#include <hip/hip_bf16.h>

#define NN 8192
#define DIN 256
#define DOUT 64

typedef __attribute__((ext_vector_type(4))) float f32x4;
typedef __attribute__((ext_vector_type(8))) short short8;

__device__ __forceinline__ unsigned enc_f(float f) {
  unsigned u = __float_as_uint(f);
  return (u & 0x80000000u) ? ~u : (u | 0x80000000u);
}
__device__ __forceinline__ float dec_f(unsigned u) {
  return (u & 0x80000000u) ? __uint_as_float(u & 0x7fffffffu)
                           : __uint_as_float(~u);
}
__device__ __forceinline__ unsigned short f2bf(float f) {
  unsigned u = __float_as_uint(f);
  u += 0x7fffu + ((u >> 16) & 1u);
  return (unsigned short)(u >> 16);
}

__global__ void k_init(unsigned* dmax) { *dmax = 0u; }

// h = X@W (fp32), src = h@a[:64], dst = h@a[64:], dstmax, HT = bf16(h)^T [64][8192]
__global__ __launch_bounds__(256) void k_hw(
    const float* __restrict__ X, const float* __restrict__ W,
    const float* __restrict__ A, float* __restrict__ src,
    float* __restrict__ dst, unsigned* __restrict__ dmax,
    unsigned short* __restrict__ HT) {
  __shared__ float Wl[DIN * DOUT];  // 64 KB
  const int tid = threadIdx.x;
#pragma unroll
  for (int i = 0; i < 16; ++i)
    ((f32x4*)Wl)[tid + 256 * i] = ((const f32x4*)W)[tid + 256 * i];
  __syncthreads();
  const int rg = tid >> 3, q = tid & 7;
  const int row0 = blockIdx.x * 128 + rg * 4;  // 4 rows per thread, 8 d-cols
  float acc[4][8];
#pragma unroll
  for (int i = 0; i < 4; ++i)
#pragma unroll
    for (int d = 0; d < 8; ++d) acc[i][d] = 0.f;
  for (int k4 = 0; k4 < DIN / 4; ++k4) {
    f32x4 xv[4];
#pragma unroll
    for (int i = 0; i < 4; ++i)
      xv[i] = ((const f32x4*)(X + (size_t)(row0 + i) * DIN))[k4];
#pragma unroll
    for (int kk = 0; kk < 4; ++kk) {
      const f32x4 w0 = *(const f32x4*)&Wl[(k4 * 4 + kk) * DOUT + q * 8];
      const f32x4 w1 = *(const f32x4*)&Wl[(k4 * 4 + kk) * DOUT + q * 8 + 4];
#pragma unroll
      for (int i = 0; i < 4; ++i) {
        const float x = xv[i][kk];
#pragma unroll
        for (int d = 0; d < 4; ++d) {
          acc[i][d] += x * w0[d];
          acc[i][d + 4] += x * w1[d];
        }
      }
    }
  }
  const f32x4 as0 = *(const f32x4*)&A[q * 8];
  const f32x4 as1 = *(const f32x4*)&A[q * 8 + 4];
  const f32x4 ad0 = *(const f32x4*)&A[DOUT + q * 8];
  const f32x4 ad1 = *(const f32x4*)&A[DOUT + q * 8 + 4];
  float sv[4], dv[4];
#pragma unroll
  for (int i = 0; i < 4; ++i) {
    float s = 0.f, d = 0.f;
#pragma unroll
    for (int e = 0; e < 4; ++e) {
      s += acc[i][e] * as0[e] + acc[i][e + 4] * as1[e];
      d += acc[i][e] * ad0[e] + acc[i][e + 4] * ad1[e];
    }
    sv[i] = s; dv[i] = d;
  }
#pragma unroll
  for (int m = 1; m < 8; m <<= 1) {
#pragma unroll
    for (int i = 0; i < 4; ++i) {
      sv[i] += __shfl_xor(sv[i], m);
      dv[i] += __shfl_xor(dv[i], m);
    }
  }
  if (q == 0) {
#pragma unroll
    for (int i = 0; i < 4; ++i) {
      src[row0 + i] = sv[i];
      dst[row0 + i] = dv[i];
    }
  }
  float dm = fmaxf(fmaxf(dv[0], dv[1]), fmaxf(dv[2], dv[3]));
#pragma unroll
  for (int m = 8; m < 64; m <<= 1) dm = fmaxf(dm, __shfl_xor(dm, m));
  if ((tid & 63) == 0) atomicMax(dmax, enc_f(dm));
#pragma unroll
  for (int i = 0; i < 4; ++i)
#pragma unroll
    for (int d = 0; d < 8; ++d)
      HT[(size_t)(q * 8 + d) * NN + row0 + i] = f2bf(acc[i][d]);
}

// Fused masked-softmax-numerator @ H via MFMA; K-chunked partials.
// Wave tile: 16 rows x 64 d, streaming 32 j per step.
__global__ __launch_bounds__(256) void k_att(
    const int* __restrict__ adj, const float* __restrict__ src,
    const float* __restrict__ dst, const unsigned* __restrict__ dmax,
    const unsigned short* __restrict__ HT, float* __restrict__ pacc,
    float* __restrict__ ps, int nchunk) {
  const int tid = threadIdx.x;
  const int wid = tid >> 6, lane = tid & 63;
  const int rowtile = blockIdx.x * 64 + wid * 16;
  const int c = blockIdx.y;
  const int CL = NN / nchunk;
  const int jbeg = c * CL, jend = jbeg + CL;
  const int l15 = lane & 15, kc = lane >> 4;
  const int arow = rowtile + l15;
  const float srci = src[arow];
  const float dmx = dec_f(*dmax);
  const float e0 = srci + dmx;
  const float mi = fmaxf(e0, 0.2f * e0);  // upper bound of leakyrelu scores
  f32x4 acc0 = {0.f, 0.f, 0.f, 0.f};
  f32x4 acc1 = acc0, acc2 = acc0, acc3 = acc0;
  float sac = 0.f;
  const int* __restrict__ arp = adj + (size_t)arow * NN;
  const unsigned short* __restrict__ hb0 = HT + (size_t)l15 * NN;
  for (int jt = jbeg; jt < jend; jt += 32) {
    const int jb = jt + kc * 8;
    const int4 av0 = *(const int4*)(arp + jb);
    const int4 av1 = *(const int4*)(arp + jb + 4);
    const float4 dd0 = *(const float4*)(dst + jb);
    const float4 dd1 = *(const float4*)(dst + jb + 4);
    const int va[8] = {av0.x, av0.y, av0.z, av0.w, av1.x, av1.y, av1.z, av1.w};
    const float vd[8] = {dd0.x, dd0.y, dd0.z, dd0.w,
                         dd1.x, dd1.y, dd1.z, dd1.w};
    short8 af;
#pragma unroll
    for (int e = 0; e < 8; ++e) {
      const float ee = srci + vd[e];
      const float y = fmaxf(ee, 0.2f * ee);  // leakyrelu(0.2)
      const float pv = (va[e] > 0) ? __expf(y - mi) : 0.f;
      sac += pv;
      af[e] = (short)f2bf(pv);
    }
    const short8 bf0 = *(const short8*)(hb0 + jb);
    const short8 bf1 = *(const short8*)(hb0 + 16 * NN + jb);
    const short8 bf2 = *(const short8*)(hb0 + 32 * NN + jb);
    const short8 bf3 = *(const short8*)(hb0 + 48 * NN + jb);
    acc0 = __builtin_amdgcn_mfma_f32_16x16x32_bf16(af, bf0, acc0, 0, 0, 0);
    acc1 = __builtin_amdgcn_mfma_f32_16x16x32_bf16(af, bf1, acc1, 0, 0, 0);
    acc2 = __builtin_amdgcn_mfma_f32_16x16x32_bf16(af, bf2, acc2, 0, 0, 0);
    acc3 = __builtin_amdgcn_mfma_f32_16x16x32_bf16(af, bf3, acc3, 0, 0, 0);
  }
  float st = sac;
  st += __shfl_xor(st, 16);
  st += __shfl_xor(st, 32);
  if (lane < 16) ps[(size_t)c * NN + arow] = st;
  const int orow = rowtile + kc * 4;  // C/D: col=lane&15, row=(lane>>4)*4+reg
  float* __restrict__ pb = pacc + ((size_t)c * NN + orow) * DOUT + l15;
#pragma unroll
  for (int v = 0; v < 4; ++v) {
    pb[(size_t)v * DOUT + 0] = acc0[v];
    pb[(size_t)v * DOUT + 16] = acc1[v];
    pb[(size_t)v * DOUT + 32] = acc2[v];
    pb[(size_t)v * DOUT + 48] = acc3[v];
  }
}

__global__ __launch_bounds__(256) void k_fin(const float* __restrict__ pacc,
                                             const float* __restrict__ ps,
                                             float* __restrict__ out,
                                             int nchunk) {
  const int idx = blockIdx.x * 256 + threadIdx.x;
  const int i = idx >> 6;
  float ss = 0.f, as = 0.f;
  for (int c = 0; c < nchunk; ++c) {
    ss += ps[(size_t)c * NN + i];
    as += pacc[(size_t)c * NN * DOUT + idx];
  }
  const float v = as / ss;
  out[idx] = v > 0.f ? v : (__expf(v) - 1.f);
}

extern "C" void kernel_launch(void* const* d_in, const int* in_sizes, int n_in,
                              void* d_out, int out_size, void* d_ws,
                              size_t ws_size, hipStream_t stream) {
  const float* X = (const float*)d_in[0];
  const int* adj = (const int*)d_in[1];
  const float* W = (const float*)d_in[2];
  const float* A = (const float*)d_in[3];
  float* out = (float*)d_out;
  char* ws = (char*)d_ws;
  float* src = (float*)(ws);
  float* dst = (float*)(ws + (32u << 10));
  unsigned* dmax = (unsigned*)(ws + (64u << 10));
  unsigned short* HT = (unsigned short*)(ws + (128u << 10));
  float* pacc = (float*)(ws + (2u << 20));
  int nchunk = 8;
  while (nchunk > 1 &&
         (size_t)(2u << 20) +
                 (size_t)nchunk * (size_t)(NN * DOUT + NN) * 4 >
             ws_size)
    nchunk >>= 1;
  float* ps = pacc + (size_t)nchunk * NN * DOUT;
  k_init<<<1, 1, 0, stream>>>(dmax);
  k_hw<<<NN / 128, 256, 0, stream>>>(X, W, A, src, dst, dmax, HT);
  k_att<<<dim3(NN / 64, nchunk), 256, 0, stream>>>(adj, src, dst, dmax, HT,
                                                   pacc, ps, nchunk);
  k_fin<<<NN * DOUT / 256, 256, 0, stream>>>(pacc, ps, out, nchunk);
}